// Round 4
// baseline (4449.031 us; speedup 1.0000x reference)
//
#include <hip/hip_runtime.h>
#include <hip/hip_bf16.h>

// Problem constants (B=8, N=1024, D=512, H=8, HD=64, E=4096, NE=8, NSH=2, TOPK=2, DH=1024)
// ALL inputs/outputs are float32 (reference is pure jnp.float32).
#define TT 8192      // B*N tokens
#define DD 512

typedef unsigned short u16;

__device__ __forceinline__ float b2f(u16 u) {
  union { unsigned int i; float f; } w; w.i = ((unsigned int)u) << 16; return w.f;
}
__device__ __forceinline__ u16 f2b(float f) {
  union { float f; unsigned int i; } w; w.f = f;
  unsigned int x = w.i;
  unsigned int r = (x + 0x7FFFu + ((x >> 16) & 1u)) >> 16;
  if ((x & 0x7F800000u) == 0x7F800000u) r = x >> 16;  // inf/nan passthrough
  return (u16)r;
}

__device__ __forceinline__ void blockReduce2(float& a, float& b, float* s4a, float* s4b) {
  #pragma unroll
  for (int off = 32; off; off >>= 1) { a += __shfl_xor(a, off); b += __shfl_xor(b, off); }
  int wid = threadIdx.x >> 6;
  if ((threadIdx.x & 63) == 0) { s4a[wid] = a; s4b[wid] = b; }
  __syncthreads();
  a = s4a[0] + s4a[1] + s4a[2] + s4a[3];
  b = s4b[0] + s4b[1] + s4b[2] + s4b[3];
}

// ---- zero small scratch (esum 4096 floats + cnt 16 ints) ----
__global__ __launch_bounds__(256) void k_zero(float* __restrict__ esum, int* __restrict__ cnt) {
  int idx = blockIdx.x * 256 + threadIdx.x;
  if (idx < 4096) esum[idx] = 0.f;
  else if (idx < 4112) cnt[idx - 4096] = 0;
}

// ---- edge sum over E=4096 edges, [B,E,D] -> [B,D] (atomics over e-chunks) ----
__global__ __launch_bounds__(256) void k_esum(const float* __restrict__ ef, float* __restrict__ esum) {
  int b = blockIdx.x, ec = blockIdx.y, tid = threadIdx.x;
  float a0 = 0.f, a1 = 0.f;
  const float* base = ef + ((size_t)b * 4096 + (size_t)ec * 128) * 512;
  for (int e = 0; e < 128; ++e) {
    a0 += base[(size_t)e * 512 + tid];
    a1 += base[(size_t)e * 512 + tid + 256];
  }
  atomicAdd(&esum[b * 512 + tid], a0);
  atomicAdd(&esum[b * 512 + tid + 256], a1);
}

// ---- einj[b,dp] = (esum[b,:]/E) @ B_w[:,dp] + B_b[dp] ----
__global__ __launch_bounds__(256) void k_einj(const float* __restrict__ esum,
                                              const float* __restrict__ Bw, const float* __restrict__ Bb,
                                              float* __restrict__ einj) {
  int idx = blockIdx.x * 256 + threadIdx.x;
  int b = idx >> 9, dp = idx & 511;
  float a = Bb[dp];
  const float inv = 1.f / 4096.f;
  for (int d = 0; d < 512; ++d)
    a = fmaf(esum[b * 512 + d] * inv, Bw[d * 512 + dp], a);
  einj[idx] = a;
}

// ---- per-segment h_lti = LN(-exp(log_A)*h + einj); out is segment-local ----
__global__ __launch_bounds__(256) void k_lti(const float* __restrict__ h, const float* __restrict__ lA,
                                             const float* __restrict__ einj,
                                             const float* __restrict__ g, const float* __restrict__ be,
                                             float* __restrict__ out, int seg0) {
  __shared__ float sa[4], sb[4];
  int rowg = seg0 + blockIdx.x, b = rowg >> 10, tid = threadIdx.x;
  int d0 = tid, d1 = tid + 256;
  size_t gbase = (size_t)rowg * 512;
  size_t lbase = (size_t)blockIdx.x * 512;
  float v0 = -expf(lA[d0]) * h[gbase + d0] + einj[b * 512 + d0];
  float v1 = -expf(lA[d1]) * h[gbase + d1] + einj[b * 512 + d1];
  float s = v0 + v1, ss = v0 * v0 + v1 * v1;
  blockReduce2(s, ss, sa, sb);
  float mu = s * (1.f / 512.f);
  float var = fmaxf(ss * (1.f / 512.f) - mu * mu, 0.f);
  float r = rsqrtf(var + 1e-5f);
  out[lbase + d0] = (v0 - mu) * r * g[d0] + be[d0];
  out[lbase + d1] = (v1 - mu) * r * g[d1] + be[d1];
}

// ---- residual LN: out = LN(A + B); f32 output ----
__global__ __launch_bounds__(256) void k_ln_res(const float* __restrict__ A, const float* __restrict__ Bv,
                                                const float* __restrict__ g, const float* __restrict__ be,
                                                float* __restrict__ outf) {
  __shared__ float sa[4], sb[4];
  int tid = threadIdx.x, d0 = tid, d1 = tid + 256;
  size_t base = (size_t)blockIdx.x * 512;
  float v0 = A[base + d0] + Bv[base + d0];
  float v1 = A[base + d1] + Bv[base + d1];
  float s = v0 + v1, ss = v0 * v0 + v1 * v1;
  blockReduce2(s, ss, sa, sb);
  float mu = s * (1.f / 512.f);
  float var = fmaxf(ss * (1.f / 512.f) - mu * mu, 0.f);
  float r = rsqrtf(var + 1e-5f);
  outf[base + d0] = (v0 - mu) * r * g[d0] + be[d0];
  outf[base + d1] = (v1 - mu) * r * g[d1] + be[d1];
}

// ---- dense GEMM: C[M,N] = act(X[M,K] @ W[K,N] + bias); W,bias f32 ----
// 64x64 tile, BK=16, 256 threads, 4x4 micro-tile.
// ACT: 0 none, 1 silu, 2 tanh. XBF16: X is bf16 staging. OUT16: write bf16 staging.
template<int ACT, int ACCUM, int XBF16, int OUT16>
__global__ __launch_bounds__(256) void gemm_dense(const float* __restrict__ X, const u16* __restrict__ Xb,
                                                  const float* __restrict__ W, const float* __restrict__ bias,
                                                  float* __restrict__ C, u16* __restrict__ C16,
                                                  int M, int K, int N) {
  __shared__ float Xs[16][68];
  __shared__ float Ws[16][68];
  const int bm = blockIdx.y << 6, bn = blockIdx.x << 6;
  const int tid = threadIdx.x;
  const int ty = tid >> 4, tx = tid & 15;
  const int mload = tid >> 2, k4 = (tid & 3) << 2;
  const int kw = tid >> 4, n4 = (tid & 15) << 2;
  float acc[4][4] = {};
  for (int k0 = 0; k0 < K; k0 += 16) {
    __syncthreads();
    if (XBF16) {
      ushort4 xv = *(const ushort4*)(Xb + (size_t)(bm + mload) * K + k0 + k4);
      Xs[k4 + 0][mload] = b2f(xv.x); Xs[k4 + 1][mload] = b2f(xv.y);
      Xs[k4 + 2][mload] = b2f(xv.z); Xs[k4 + 3][mload] = b2f(xv.w);
    } else {
      float4 xv = *(const float4*)(X + (size_t)(bm + mload) * K + k0 + k4);
      Xs[k4 + 0][mload] = xv.x; Xs[k4 + 1][mload] = xv.y;
      Xs[k4 + 2][mload] = xv.z; Xs[k4 + 3][mload] = xv.w;
    }
    *(float4*)&Ws[kw][n4] = *(const float4*)(W + (size_t)(k0 + kw) * N + bn + n4);
    __syncthreads();
    #pragma unroll
    for (int kk = 0; kk < 16; ++kk) {
      const float4 a4 = *(const float4*)&Xs[kk][ty << 2];
      const float4 b4 = *(const float4*)&Ws[kk][tx << 2];
      const float av[4] = {a4.x, a4.y, a4.z, a4.w};
      const float bw[4] = {b4.x, b4.y, b4.z, b4.w};
      #pragma unroll
      for (int i = 0; i < 4; ++i)
        #pragma unroll
        for (int j = 0; j < 4; ++j)
          acc[i][j] = fmaf(av[i], bw[j], acc[i][j]);
    }
  }
  const int r0 = bm + (ty << 2), c0 = bn + (tx << 2);
  #pragma unroll
  for (int i = 0; i < 4; ++i) {
    float vj[4];
    #pragma unroll
    for (int j = 0; j < 4; ++j) {
      float v = acc[i][j] + bias[c0 + j];
      if (ACT == 1) v = v / (1.f + expf(-v));
      else if (ACT == 2) v = tanhf(v);
      vj[j] = v;
    }
    if (OUT16) {
      u16* cp = C16 + (size_t)(r0 + i) * N + c0;
      ushort4 o; o.x = f2b(vj[0]); o.y = f2b(vj[1]); o.z = f2b(vj[2]); o.w = f2b(vj[3]);
      *(ushort4*)cp = o;
    } else {
      float* cp = C + (size_t)(r0 + i) * N + c0;
      if (ACCUM) { cp[0] += vj[0]; cp[1] += vj[1]; cp[2] += vj[2]; cp[3] += vj[3]; }
      else *(float4*)cp = make_float4(vj[0], vj[1], vj[2], vj[3]);
    }
  }
}

// ---- per-node head attention: scores = q@k^T/8 over [H=8,HD=64], softmax, @v ----
__global__ __launch_bounds__(64) void k_attn(const float* __restrict__ q, const float* __restrict__ k,
                                             const float* __restrict__ v, float* __restrict__ ao) {
  __shared__ float qs[512], ks[512], vs[512], at[64];
  size_t t = blockIdx.x;
  int lane = threadIdx.x;
  for (int i = lane; i < 512; i += 64) {
    qs[i] = q[t * 512 + i]; ks[i] = k[t * 512 + i]; vs[i] = v[t * 512 + i];
  }
  __syncthreads();
  int h = lane >> 3, g = lane & 7;
  float s = 0.f;
  #pragma unroll 8
  for (int d = 0; d < 64; ++d) s = fmaf(qs[h * 64 + d], ks[g * 64 + d], s);
  s *= 0.125f;  // 1/sqrt(64)
  float m = s;
  #pragma unroll
  for (int off = 1; off < 8; off <<= 1) m = fmaxf(m, __shfl_xor(m, off));
  float ex = expf(s - m);
  float sum = ex;
  #pragma unroll
  for (int off = 1; off < 8; off <<= 1) sum += __shfl_xor(sum, off);
  at[lane] = ex / sum;
  __syncthreads();
  #pragma unroll
  for (int j = 0; j < 8; ++j) {
    int d = lane + j * 64, hh = d >> 6, hd = d & 63;
    float acc = 0.f;
    #pragma unroll
    for (int gg = 0; gg < 8; ++gg) acc = fmaf(at[hh * 8 + gg], vs[gg * 64 + hd], acc);
    ao[t * 512 + d] = acc;
  }
}

// ---- gate: logits -> softmax -> top2 -> renorm; per-expert token lists (hardened) ----
__global__ __launch_bounds__(256) void k_gate(const float* __restrict__ h2, const float* __restrict__ gw,
                                              const float* __restrict__ gb, float* __restrict__ probs,
                                              float* __restrict__ wlist, int* __restrict__ toklist,
                                              int* __restrict__ cnt) {
  int lane = threadIdx.x & 63, wid = threadIdx.x >> 6;
  int t = blockIdx.x * 4 + wid;
  const float* x = h2 + (size_t)t * 512;
  float acc[8] = {};
  for (int d = lane; d < 512; d += 64) {
    float xv = x[d];
    float4 g0 = *(const float4*)(gw + d * 8);
    float4 g1 = *(const float4*)(gw + d * 8 + 4);
    acc[0] = fmaf(xv, g0.x, acc[0]); acc[1] = fmaf(xv, g0.y, acc[1]);
    acc[2] = fmaf(xv, g0.z, acc[2]); acc[3] = fmaf(xv, g0.w, acc[3]);
    acc[4] = fmaf(xv, g1.x, acc[4]); acc[5] = fmaf(xv, g1.y, acc[5]);
    acc[6] = fmaf(xv, g1.z, acc[6]); acc[7] = fmaf(xv, g1.w, acc[7]);
  }
  #pragma unroll
  for (int off = 32; off; off >>= 1)
    #pragma unroll
    for (int e = 0; e < 8; ++e) acc[e] += __shfl_xor(acc[e], off);
  if (lane == 0) {
    float m = -1e30f;
    #pragma unroll
    for (int e = 0; e < 8; ++e) { acc[e] += gb[e]; m = fmaxf(m, acc[e]); }
    float p[8], sum = 0.f;
    #pragma unroll
    for (int e = 0; e < 8; ++e) { p[e] = expf(acc[e] - m); sum += p[e]; }
    float inv = 1.f / sum;
    #pragma unroll
    for (int e = 0; e < 8; ++e) { p[e] *= inv; probs[t * 8 + e] = p[e]; }
    int i1 = 0; float m1 = p[0];
    #pragma unroll
    for (int e = 1; e < 8; ++e) if (p[e] > m1) { m1 = p[e]; i1 = e; }  // ties -> lowest idx
    int i2 = -1; float m2 = -1.f;
    #pragma unroll
    for (int e = 0; e < 8; ++e) if (e != i1 && p[e] > m2) { m2 = p[e]; i2 = e; }
    if (i2 < 0) i2 = (i1 + 1) & 7;            // NaN-safe fallback (never negative index)
    float den = m1 + m2;
    float invs = (den > 0.f) ? 1.f / den : 0.f;
    int p1 = atomicAdd(&cnt[i1], 1); if (p1 > 8191) p1 = 8191;
    toklist[i1 * 8192 + p1] = t; wlist[i1 * 8192 + p1] = m1 * invs;
    int p2 = atomicAdd(&cnt[i2], 1); if (p2 > 8191) p2 = 8191;
    toklist[i2 * 8192 + p2] = t; wlist[i2 * 8192 + p2] = m2 * invs;
  }
}

// ---- routed expert pass A: hid[chunk-local] = silu(gather(h2) @ eW1[e] + eb1[e]), bf16 out ----
__global__ __launch_bounds__(256) void k_expertA(const float* __restrict__ X, const float* __restrict__ eW1,
                                                 const float* __restrict__ eb1, const int* __restrict__ toklist,
                                                 const int* __restrict__ cnt, int e, int chunk0,
                                                 u16* __restrict__ hid) {
  int ce = cnt[e]; if (ce > 8192) ce = 8192;
  int bm = blockIdx.y << 6;
  if (chunk0 + bm >= ce) return;
  int bn = blockIdx.x << 6;
  __shared__ float Xs[16][68];
  __shared__ float Ws[16][68];
  __shared__ int rows[64];
  int tid = threadIdx.x;
  if (tid < 64) {
    int r = chunk0 + bm + tid;
    rows[tid] = toklist[e * 8192 + (r < ce ? r : chunk0)];
  }
  const float* W = eW1 + (size_t)e * 512 * 1024;
  const float* bb = eb1 + e * 1024;
  const int ty = tid >> 4, tx = tid & 15;
  const int mload = tid >> 2, k4 = (tid & 3) << 2;
  const int kw = tid >> 4, n4 = (tid & 15) << 2;
  float acc[4][4] = {};
  for (int k0 = 0; k0 < 512; k0 += 16) {
    __syncthreads();
    float4 xv = *(const float4*)(X + (size_t)rows[mload] * 512 + k0 + k4);
    Xs[k4 + 0][mload] = xv.x; Xs[k4 + 1][mload] = xv.y;
    Xs[k4 + 2][mload] = xv.z; Xs[k4 + 3][mload] = xv.w;
    *(float4*)&Ws[kw][n4] = *(const float4*)(W + (size_t)(k0 + kw) * 1024 + bn + n4);
    __syncthreads();
    #pragma unroll
    for (int kk = 0; kk < 16; ++kk) {
      const float4 a4 = *(const float4*)&Xs[kk][ty << 2];
      const float4 b4 = *(const float4*)&Ws[kk][tx << 2];
      const float av[4] = {a4.x, a4.y, a4.z, a4.w};
      const float bw[4] = {b4.x, b4.y, b4.z, b4.w};
      #pragma unroll
      for (int i = 0; i < 4; ++i)
        #pragma unroll
        for (int j = 0; j < 4; ++j)
          acc[i][j] = fmaf(av[i], bw[j], acc[i][j]);
    }
  }
  const int c0 = bn + (tx << 2);
  #pragma unroll
  for (int i = 0; i < 4; ++i) {
    int rl = bm + (ty << 2) + i;             // chunk-local row
    if (chunk0 + rl < ce) {
      ushort4 o;
      float v0 = acc[i][0] + bb[c0 + 0]; o.x = f2b(v0 / (1.f + expf(-v0)));
      float v1 = acc[i][1] + bb[c0 + 1]; o.y = f2b(v1 / (1.f + expf(-v1)));
      float v2 = acc[i][2] + bb[c0 + 2]; o.z = f2b(v2 / (1.f + expf(-v2)));
      float v3 = acc[i][3] + bb[c0 + 3]; o.w = f2b(v3 / (1.f + expf(-v3)));
      *(ushort4*)(hid + (size_t)rl * 1024 + c0) = o;
    }
  }
}

// ---- routed expert pass B: moe[tok] += w * (hid @ eW2[e] + eb2[e]) ----
__global__ __launch_bounds__(256) void k_expertB(const u16* __restrict__ hid, const float* __restrict__ eW2,
                                                 const float* __restrict__ eb2, const int* __restrict__ toklist,
                                                 const float* __restrict__ wlist, const int* __restrict__ cnt,
                                                 int e, int chunk0, float* __restrict__ moe) {
  int ce = cnt[e]; if (ce > 8192) ce = 8192;
  int bm = blockIdx.y << 6;
  if (chunk0 + bm >= ce) return;
  int bn = blockIdx.x << 6;
  __shared__ float Xs[16][68];
  __shared__ float Ws[16][68];
  int tid = threadIdx.x;
  const float* W = eW2 + (size_t)e * 1024 * 512;
  const float* bb = eb2 + e * 512;
  const int ty = tid >> 4, tx = tid & 15;
  const int mload = tid >> 2, k4 = (tid & 3) << 2;
  const int kw = tid >> 4, n4 = (tid & 15) << 2;
  float acc[4][4] = {};
  for (int k0 = 0; k0 < 1024; k0 += 16) {
    __syncthreads();
    int rl = bm + mload; if (chunk0 + rl >= ce) rl = bm;  // clamp to valid chunk row
    ushort4 xv = *(const ushort4*)(hid + (size_t)rl * 1024 + k0 + k4);
    Xs[k4 + 0][mload] = b2f(xv.x); Xs[k4 + 1][mload] = b2f(xv.y);
    Xs[k4 + 2][mload] = b2f(xv.z); Xs[k4 + 3][mload] = b2f(xv.w);
    *(float4*)&Ws[kw][n4] = *(const float4*)(W + (size_t)(k0 + kw) * 512 + bn + n4);
    __syncthreads();
    #pragma unroll
    for (int kk = 0; kk < 16; ++kk) {
      const float4 a4 = *(const float4*)&Xs[kk][ty << 2];
      const float4 b4 = *(const float4*)&Ws[kk][tx << 2];
      const float av[4] = {a4.x, a4.y, a4.z, a4.w};
      const float bw[4] = {b4.x, b4.y, b4.z, b4.w};
      #pragma unroll
      for (int i = 0; i < 4; ++i)
        #pragma unroll
        for (int j = 0; j < 4; ++j)
          acc[i][j] = fmaf(av[i], bw[j], acc[i][j]);
    }
  }
  const int c0 = bn + (tx << 2);
  #pragma unroll
  for (int i = 0; i < 4; ++i) {
    int rl = bm + (ty << 2) + i;
    int rg = chunk0 + rl;
    if (rg < ce) {
      int tok = toklist[e * 8192 + rg] & 8191;
      float w = wlist[e * 8192 + rg];
      #pragma unroll
      for (int j = 0; j < 4; ++j) {
        float v = (acc[i][j] + bb[c0 + j]) * w;
        atomicAdd(&moe[(size_t)tok * 512 + c0 + j], v);
      }
    }
  }
}

// ---- halt head: logit = hh[t,:] @ hW2 + hb2; sigmoid; write both halt outputs ----
__global__ __launch_bounds__(256) void k_halt(const u16* __restrict__ hh, const float* __restrict__ hW2,
                                              const float* __restrict__ hb2, float* __restrict__ out) {
  int lane = threadIdx.x & 63, wid = threadIdx.x >> 6;
  int t = blockIdx.x * 4 + wid;
  const u16* x = hh + (size_t)t * 256;
  float a = b2f(x[lane]) * hW2[lane] + b2f(x[lane + 64]) * hW2[lane + 64] +
            b2f(x[lane + 128]) * hW2[lane + 128] + b2f(x[lane + 192]) * hW2[lane + 192];
  #pragma unroll
  for (int off = 32; off; off >>= 1) a += __shfl_xor(a, off);
  if (lane == 0) {
    float p = 1.f / (1.f + expf(-(a + hb2[0])));
    out[4194304 + t] = p;          // cumsum_halt
    out[4194304 + 8192 + t] = p;   // halt_prob
  }
}

// ---- scalar: stab + aux loss ----
__global__ __launch_bounds__(256) void k_final(const float* __restrict__ probs, const int* __restrict__ cnt,
                                               const float* __restrict__ lA, float* __restrict__ out) {
  __shared__ float sp[4][8];
  __shared__ float sm[4];
  int tid = threadIdx.x, lane = tid & 63, wid = tid >> 6;
  float part[8] = {};
  for (int i = tid; i < 8192; i += 256) {
    const float* p = probs + i * 8;
    #pragma unroll
    for (int e = 0; e < 8; ++e) part[e] += p[e];
  }
  #pragma unroll
  for (int off = 32; off; off >>= 1)
    #pragma unroll
    for (int e = 0; e < 8; ++e) part[e] += __shfl_xor(part[e], off);
  float mx = 0.f;
  for (int d = tid; d < 512; d += 256) mx = fmaxf(mx, expf(lA[d]));
  #pragma unroll
  for (int off = 32; off; off >>= 1) mx = fmaxf(mx, __shfl_xor(mx, off));
  if (lane == 0) {
    #pragma unroll
    for (int e = 0; e < 8; ++e) sp[wid][e] = part[e];
    sm[wid] = mx;
  }
  __syncthreads();
  if (tid == 0) {
    float loss = 0.f;
    for (int e = 0; e < 8; ++e) {
      float pm = (sp[0][e] + sp[1][e] + sp[2][e] + sp[3][e]) * (1.f / 8192.f);
      int c = cnt[e]; if (c > 8192) c = 8192;
      loss += (float)c * (1.f / 8192.f) * pm;
    }
    loss *= 0.01f * 8.f;
    float mall = fmaxf(fmaxf(sm[0], sm[1]), fmaxf(sm[2], sm[3]));
    out[4194304 + 16384] = fmaxf(mall - 0.95f, 0.f) + loss;
  }
}

extern "C" void kernel_launch(void* const* d_in, const int* in_sizes, int n_in,
                              void* d_out, int out_size, void* d_ws, size_t ws_size,
                              hipStream_t stream) {
  const float* h   = (const float*)d_in[0];
  const float* ef  = (const float*)d_in[1];
  const float* lA  = (const float*)d_in[2];
  const float* Bw  = (const float*)d_in[3];
  const float* Bb  = (const float*)d_in[4];
  const float* Wq  = (const float*)d_in[5];  const float* bq  = (const float*)d_in[6];
  const float* Wk  = (const float*)d_in[7];  const float* bk  = (const float*)d_in[8];
  const float* Wv  = (const float*)d_in[9];  const float* bv  = (const float*)d_in[10];
  const float* Wo  = (const float*)d_in[11]; const float* bo  = (const float*)d_in[12];
  const float* n1g = (const float*)d_in[13]; const float* n1b = (const float*)d_in[14];
  const float* n2g = (const float*)d_in[15]; const float* n2b = (const float*)d_in[16];
  const float* n3g = (const float*)d_in[17]; const float* n3b = (const float*)d_in[18];
  const float* gw  = (const float*)d_in[19]; const float* gb  = (const float*)d_in[20];
  const float* eW1 = (const float*)d_in[21]; const float* eb1 = (const float*)d_in[22];
  const float* eW2 = (const float*)d_in[23]; const float* eb2 = (const float*)d_in[24];
  const float* sW1 = (const float*)d_in[25]; const float* sb1 = (const float*)d_in[26];
  const float* sW2 = (const float*)d_in[27]; const float* sb2 = (const float*)d_in[28];
  const float* hW1 = (const float*)d_in[29]; const float* hb1 = (const float*)d_in[30];
  const float* hW2 = (const float*)d_in[31]; const float* hb2 = (const float*)d_in[32];
  float* out = (float*)d_out;
  float* ws = (float*)d_ws;

  // ---- fixed minimal workspace layout (~37 MB total) ----
  // [0, R)        f_h2  (f32)   -- persists from attention through final LN
  // [R, 2R)       f_moe (f32)   -- expert-output accumulator
  // [2R, 2R+A)    arena (4 MB = 1,048,576 floats), reused in sequence:
  //     attention per-segment (S=512): hlti | q | k | v  (4 x 262,144 floats)
  //         ao aliases q (per-block safe), hp aliases k (k dead after k_attn)
  //     expert hid: 2048 x 1024 bf16; halt hidden: 8192 x 256 bf16
  // [2R+A, ...)   small: esum | einj | probs | wlist | ints(cnt, toklist)
  const size_t R = (size_t)TT * DD;          // 4,194,304 floats
  const size_t ARENA = 1048576;
  const int S = 512;                          // attention segment tokens
  const int CAP = 2048;                       // expert chunk rows

  float* f_h2  = ws;
  float* f_moe = ws + R;
  float* arena = ws + 2 * R;
  float* f_hlti = arena;
  float* f_q   = arena + 262144;
  float* f_k   = arena + 524288;
  float* f_v   = arena + 786432;
  float* f_ao  = f_q;                         // alias (safe: k_attn stages in LDS first)
  float* f_hp  = f_k;                         // alias (k dead after k_attn)
  u16*   f_hid = (u16*)arena;                 // expert phase
  u16*   f_hh  = (u16*)arena;                 // halt phase
  float* smr   = ws + 2 * R + ARENA;
  float* f_esum = smr;
  float* f_einj = smr + 4096;
  float* f_probs = smr + 8192;
  float* f_wlist = smr + 8192 + 65536;
  int* ip = (int*)(smr + 8192 + 2 * 65536);
  int* cnt = ip; int* toklist = ip + 16;

  // ---- zero scratch ----
  k_zero<<<17, 256, 0, stream>>>(f_esum, cnt);

  // ---- LTI prep (edge mean is batch-global, compute once) ----
  k_esum<<<dim3(8, 32), 256, 0, stream>>>(ef, f_esum);
  k_einj<<<16, 256, 0, stream>>>(f_esum, Bw, Bb, f_einj);

  // ---- LTI + attention, segmented (S tokens at a time) ----
  for (int s = 0; s < TT / S; ++s) {
    int seg0 = s * S;
    k_lti<<<S, 256, 0, stream>>>(h, lA, f_einj, n1g, n1b, f_hlti, seg0);
    gemm_dense<0,0,0,0><<<dim3(8, S/64), 256, 0, stream>>>(f_hlti, nullptr, Wq, bq, f_q, nullptr, S, 512, 512);
    gemm_dense<0,0,0,0><<<dim3(8, S/64), 256, 0, stream>>>(f_hlti, nullptr, Wk, bk, f_k, nullptr, S, 512, 512);
    gemm_dense<0,0,0,0><<<dim3(8, S/64), 256, 0, stream>>>(f_hlti, nullptr, Wv, bv, f_v, nullptr, S, 512, 512);
    k_attn<<<S, 64, 0, stream>>>(f_q, f_k, f_v, f_ao);
    gemm_dense<0,0,0,0><<<dim3(8, S/64), 256, 0, stream>>>(f_ao, nullptr, Wo, bo, f_hp, nullptr, S, 512, 512);
    k_ln_res<<<S, 256, 0, stream>>>(f_hlti, f_hp, n2g, n2b, f_h2 + (size_t)seg0 * 512);
  }

  // ---- MoE gate + routing lists ----
  k_gate<<<TT / 4, 256, 0, stream>>>(f_h2, gw, gb, f_probs, f_wlist, toklist, cnt);

  // ---- shared experts (dense, chunked through the 4 MB hid buffer) ----
  for (int sx = 0; sx < 2; ++sx)
    for (int c = 0; c < TT / CAP; ++c) {
      const float* xs = f_h2 + (size_t)c * CAP * 512;
      float* ms = f_moe + (size_t)c * CAP * 512;
      gemm_dense<1,0,0,1><<<dim3(16, CAP/64), 256, 0, stream>>>(
          xs, nullptr, sW1 + (size_t)sx * 524288, sb1 + sx * 1024, nullptr, f_hid, CAP, 512, 1024);
      if (sx == 0)
        gemm_dense<0,0,1,0><<<dim3(8, CAP/64), 256, 0, stream>>>(
            nullptr, f_hid, sW2, sb2, ms, nullptr, CAP, 1024, 512);
      else
        gemm_dense<0,1,1,0><<<dim3(8, CAP/64), 256, 0, stream>>>(
            nullptr, f_hid, sW2 + 524288, sb2 + 512, ms, nullptr, CAP, 1024, 512);
    }

  // ---- routed experts (top-2 only, gathered, chunked) ----
  for (int e = 0; e < 8; ++e)
    for (int c = 0; c < TT / CAP; ++c) {
      k_expertA<<<dim3(16, CAP/64), 256, 0, stream>>>(f_h2, eW1, eb1, toklist, cnt, e, c * CAP, f_hid);
      k_expertB<<<dim3(8, CAP/64), 256, 0, stream>>>(f_hid, eW2, eb2, toklist, f_wlist, cnt, e, c * CAP, f_moe);
    }

  // ---- final LN -> f32 h3 directly to output; halt head reads h3 from out ----
  k_ln_res<<<TT, 256, 0, stream>>>(f_h2, f_moe, n3g, n3b, out);
  gemm_dense<2,0,0,1><<<dim3(4, 128), 256, 0, stream>>>(out, nullptr, hW1, hb1, nullptr, f_hh, TT, 512, 256);
  k_halt<<<TT / 4, 256, 0, stream>>>(f_hh, hW2, hb2, out);
  k_final<<<1, 256, 0, stream>>>(f_probs, cnt, lA, out);
}

// Round 6
// 1026.186 us; speedup vs baseline: 4.3355x; 4.3355x over previous
//
#include <hip/hip_runtime.h>
#include <hip/hip_bf16.h>

// Problem constants (B=8, N=1024, D=512, H=8, HD=64, E=4096, NE=8, NSH=2, TOPK=2, DH=1024)
// ALL inputs/outputs are float32.
#define TT 8192
#define DD 512

typedef unsigned short u16;
typedef __attribute__((ext_vector_type(8))) short short8;
typedef __attribute__((ext_vector_type(4))) float f32x4;

__device__ __forceinline__ u16 f2b(float f) {
  union { float f; unsigned int i; } w; w.f = f;
  unsigned int x = w.i;
  unsigned int r = (x + 0x7FFFu + ((x >> 16) & 1u)) >> 16;
  if ((x & 0x7F800000u) == 0x7F800000u) r = x >> 16;
  return (u16)r;
}
__device__ __forceinline__ float b2f(u16 u) {
  union { unsigned int i; float f; } w; w.i = ((unsigned int)u) << 16; return w.f;
}

__device__ __forceinline__ void blockReduce2(float& a, float& b, float* s4a, float* s4b) {
  #pragma unroll
  for (int off = 32; off; off >>= 1) { a += __shfl_xor(a, off); b += __shfl_xor(b, off); }
  int wid = threadIdx.x >> 6;
  if ((threadIdx.x & 63) == 0) { s4a[wid] = a; s4b[wid] = b; }
  __syncthreads();
  a = s4a[0] + s4a[1] + s4a[2] + s4a[3];
  b = s4b[0] + s4b[1] + s4b[2] + s4b[3];
}

// ---- zero esum ----
__global__ __launch_bounds__(256) void k_zero(float* __restrict__ esum) {
  esum[blockIdx.x * 256 + threadIdx.x] = 0.f;
}

// ---- edge sum: [B,E,D] -> [B,D] ----
__global__ __launch_bounds__(256) void k_esum(const float* __restrict__ ef, float* __restrict__ esum) {
  int b = blockIdx.x, ec = blockIdx.y, tid = threadIdx.x;
  float a0 = 0.f, a1 = 0.f;
  const float* base = ef + ((size_t)b * 4096 + (size_t)ec * 128) * 512;
  for (int e = 0; e < 128; ++e) {
    a0 += base[(size_t)e * 512 + tid];
    a1 += base[(size_t)e * 512 + tid + 256];
  }
  atomicAdd(&esum[b * 512 + tid], a0);
  atomicAdd(&esum[b * 512 + tid + 256], a1);
}

// ---- einj[b,dp] = (esum[b,:]/E) @ B_w[:,dp] + B_b[dp] ----
__global__ __launch_bounds__(256) void k_einj(const float* __restrict__ esum,
                                              const float* __restrict__ Bw, const float* __restrict__ Bb,
                                              float* __restrict__ einj) {
  int idx = blockIdx.x * 256 + threadIdx.x;
  int b = idx >> 9, dp = idx & 511;
  float a = Bb[dp];
  const float inv = 1.f / 4096.f;
  for (int d = 0; d < 512; ++d)
    a = fmaf(esum[b * 512 + d] * inv, Bw[d * 512 + dp], a);
  einj[idx] = a;
}

// ---- h_lti = LN(-exp(log_A)*h + einj), segment-local output ----
__global__ __launch_bounds__(256) void k_lti(const float* __restrict__ h, const float* __restrict__ lA,
                                             const float* __restrict__ einj,
                                             const float* __restrict__ g, const float* __restrict__ be,
                                             float* __restrict__ out, int seg0) {
  __shared__ float sa[4], sb[4];
  int rowg = seg0 + blockIdx.x, b = rowg >> 10, tid = threadIdx.x;
  int d0 = tid, d1 = tid + 256;
  size_t gbase = (size_t)rowg * 512;
  size_t lbase = (size_t)blockIdx.x * 512;
  float v0 = -expf(lA[d0]) * h[gbase + d0] + einj[b * 512 + d0];
  float v1 = -expf(lA[d1]) * h[gbase + d1] + einj[b * 512 + d1];
  float s = v0 + v1, ss = v0 * v0 + v1 * v1;
  blockReduce2(s, ss, sa, sb);
  float mu = s * (1.f / 512.f);
  float var = fmaxf(ss * (1.f / 512.f) - mu * mu, 0.f);
  float r = rsqrtf(var + 1e-5f);
  out[lbase + d0] = (v0 - mu) * r * g[d0] + be[d0];
  out[lbase + d1] = (v1 - mu) * r * g[d1] + be[d1];
}

// ---- residual LN ----
__global__ __launch_bounds__(256) void k_ln_res(const float* __restrict__ A, const float* __restrict__ Bv,
                                                const float* __restrict__ g, const float* __restrict__ be,
                                                float* __restrict__ outf) {
  __shared__ float sa[4], sb[4];
  int tid = threadIdx.x, d0 = tid, d1 = tid + 256;
  size_t base = (size_t)blockIdx.x * 512;
  float v0 = A[base + d0] + Bv[base + d0];
  float v1 = A[base + d1] + Bv[base + d1];
  float s = v0 + v1, ss = v0 * v0 + v1 * v1;
  blockReduce2(s, ss, sa, sb);
  float mu = s * (1.f / 512.f);
  float var = fmaxf(ss * (1.f / 512.f) - mu * mu, 0.f);
  float r = rsqrtf(var + 1e-5f);
  outf[base + d0] = (v0 - mu) * r * g[d0] + be[d0];
  outf[base + d1] = (v1 - mu) * r * g[d1] + be[d1];
}

// ---- f32 vector GEMM body (64x64 tile, BK=16) — routing-critical path stays f32 ----
__device__ __forceinline__ void gemm64_f32(const float* __restrict__ X, const float* __restrict__ W,
                                           const float* __restrict__ bias, float* __restrict__ C,
                                           int K, int N, int bm, int bn) {
  __shared__ float Xs[16][68];
  __shared__ float Ws[16][68];
  const int tid = threadIdx.x;
  const int ty = tid >> 4, tx = tid & 15;
  const int mload = tid >> 2, k4 = (tid & 3) << 2;
  const int kw = tid >> 4, n4 = (tid & 15) << 2;
  float acc[4][4] = {};
  for (int k0 = 0; k0 < K; k0 += 16) {
    __syncthreads();
    float4 xv = *(const float4*)(X + (size_t)(bm + mload) * K + k0 + k4);
    Xs[k4 + 0][mload] = xv.x; Xs[k4 + 1][mload] = xv.y;
    Xs[k4 + 2][mload] = xv.z; Xs[k4 + 3][mload] = xv.w;
    *(float4*)&Ws[kw][n4] = *(const float4*)(W + (size_t)(k0 + kw) * N + bn + n4);
    __syncthreads();
    #pragma unroll
    for (int kk = 0; kk < 16; ++kk) {
      const float4 a4 = *(const float4*)&Xs[kk][ty << 2];
      const float4 b4 = *(const float4*)&Ws[kk][tx << 2];
      const float av[4] = {a4.x, a4.y, a4.z, a4.w};
      const float bw[4] = {b4.x, b4.y, b4.z, b4.w};
      #pragma unroll
      for (int i = 0; i < 4; ++i)
        #pragma unroll
        for (int j = 0; j < 4; ++j)
          acc[i][j] = fmaf(av[i], bw[j], acc[i][j]);
    }
  }
  const int r0 = bm + (ty << 2), c0 = bn + (tx << 2);
  #pragma unroll
  for (int i = 0; i < 4; ++i) {
    float4 o = make_float4(acc[i][0] + bias[c0], acc[i][1] + bias[c0 + 1],
                           acc[i][2] + bias[c0 + 2], acc[i][3] + bias[c0 + 3]);
    *(float4*)(C + (size_t)(r0 + i) * N + c0) = o;
  }
}

__global__ __launch_bounds__(256) void gemm_f32(const float* __restrict__ X, const float* __restrict__ W,
                                                const float* __restrict__ bias, float* __restrict__ C,
                                                int K, int N) {
  gemm64_f32(X, W, bias, C, K, N, blockIdx.y << 6, blockIdx.x << 6);
}

// fused QKV: blockIdx.z selects {q,k,v}
__global__ __launch_bounds__(256) void gemm_qkv(const float* __restrict__ X,
                                                const float* __restrict__ Wq, const float* __restrict__ bq,
                                                const float* __restrict__ Wk, const float* __restrict__ bk,
                                                const float* __restrict__ Wv, const float* __restrict__ bv,
                                                float* __restrict__ Cq, float* __restrict__ Ck,
                                                float* __restrict__ Cv) {
  int z = blockIdx.z;
  const float* W = z == 0 ? Wq : (z == 1 ? Wk : Wv);
  const float* b = z == 0 ? bq : (z == 1 ? bk : bv);
  float* C = z == 0 ? Cq : (z == 1 ? Ck : Cv);
  gemm64_f32(X, W, b, C, 512, 512, blockIdx.y << 6, blockIdx.x << 6);
}

// ---- per-node head attention ----
__global__ __launch_bounds__(64) void k_attn(const float* __restrict__ q, const float* __restrict__ k,
                                             const float* __restrict__ v, float* __restrict__ ao) {
  __shared__ float qs[512], ks[512], vs[512], at[64];
  size_t t = blockIdx.x;
  int lane = threadIdx.x;
  for (int i = lane; i < 512; i += 64) {
    qs[i] = q[t * 512 + i]; ks[i] = k[t * 512 + i]; vs[i] = v[t * 512 + i];
  }
  __syncthreads();
  int h = lane >> 3, g = lane & 7;
  float s = 0.f;
  #pragma unroll 8
  for (int d = 0; d < 64; ++d) s = fmaf(qs[h * 64 + d], ks[g * 64 + d], s);
  s *= 0.125f;
  float m = s;
  #pragma unroll
  for (int off = 1; off < 8; off <<= 1) m = fmaxf(m, __shfl_xor(m, off));
  float ex = expf(s - m);
  float sum = ex;
  #pragma unroll
  for (int off = 1; off < 8; off <<= 1) sum += __shfl_xor(sum, off);
  at[lane] = ex / sum;
  __syncthreads();
  #pragma unroll
  for (int j = 0; j < 8; ++j) {
    int d = lane + j * 64, hh = d >> 6, hd = d & 63;
    float acc = 0.f;
    #pragma unroll
    for (int gg = 0; gg < 8; ++gg) acc = fmaf(at[hh * 8 + gg], vs[gg * 64 + hd], acc);
    ao[t * 512 + d] = acc;
  }
}

// ---- gate phase A: probs + top2 per token, NO atomics ----
__global__ __launch_bounds__(256) void k_gateA(const float* __restrict__ h2, const float* __restrict__ gw,
                                               const float* __restrict__ gb, float* __restrict__ probs,
                                               int* __restrict__ sel, float2* __restrict__ wpair) {
  int lane = threadIdx.x & 63, wid = threadIdx.x >> 6;
  int t = blockIdx.x * 4 + wid;
  const float* x = h2 + (size_t)t * 512;
  float acc[8] = {};
  for (int d = lane; d < 512; d += 64) {
    float xv = x[d];
    float4 g0 = *(const float4*)(gw + d * 8);
    float4 g1 = *(const float4*)(gw + d * 8 + 4);
    acc[0] = fmaf(xv, g0.x, acc[0]); acc[1] = fmaf(xv, g0.y, acc[1]);
    acc[2] = fmaf(xv, g0.z, acc[2]); acc[3] = fmaf(xv, g0.w, acc[3]);
    acc[4] = fmaf(xv, g1.x, acc[4]); acc[5] = fmaf(xv, g1.y, acc[5]);
    acc[6] = fmaf(xv, g1.z, acc[6]); acc[7] = fmaf(xv, g1.w, acc[7]);
  }
  #pragma unroll
  for (int off = 32; off; off >>= 1)
    #pragma unroll
    for (int e = 0; e < 8; ++e) acc[e] += __shfl_xor(acc[e], off);
  if (lane == 0) {
    float m = -1e30f;
    #pragma unroll
    for (int e = 0; e < 8; ++e) { acc[e] += gb[e]; m = fmaxf(m, acc[e]); }
    float p[8], sum = 0.f;
    #pragma unroll
    for (int e = 0; e < 8; ++e) { p[e] = expf(acc[e] - m); sum += p[e]; }
    float inv = 1.f / sum;
    #pragma unroll
    for (int e = 0; e < 8; ++e) { p[e] *= inv; probs[t * 8 + e] = p[e]; }
    int i1 = 0; float m1 = p[0];
    #pragma unroll
    for (int e = 1; e < 8; ++e) if (p[e] > m1) { m1 = p[e]; i1 = e; }
    int i2 = -1; float m2 = -1.f;
    #pragma unroll
    for (int e = 0; e < 8; ++e) if (e != i1 && p[e] > m2) { m2 = p[e]; i2 = e; }
    if (i2 < 0) i2 = (i1 + 1) & 7;
    float den = m1 + m2;
    float invs = (den > 0.f) ? 1.f / den : 0.f;
    sel[t] = i1 | (i2 << 4);
    wpair[t] = make_float2(m1 * invs, m2 * invs);
  }
}

// ---- gate phase B: per-expert compaction via ballot prefix scan (8 blocks) ----
__global__ __launch_bounds__(256) void k_gateB(const int* __restrict__ sel, const float2* __restrict__ wpair,
                                               int* __restrict__ toklist, float* __restrict__ wlist,
                                               int* __restrict__ cnt) {
  int e = blockIdx.x;
  int tid = threadIdx.x, lane = tid & 63, wv = tid >> 6;
  __shared__ int wsum[4];
  int base = 0;
  for (int t0 = 0; t0 < 8192; t0 += 256) {
    int t = t0 + tid;
    int s = sel[t];
    int i1 = s & 15, i2 = (s >> 4) & 15;
    bool f = (i1 == e) || (i2 == e);
    float wt = (i1 == e) ? wpair[t].x : ((i2 == e) ? wpair[t].y : 0.f);
    unsigned long long m = __ballot(f);
    int rank = __popcll(m & ((1ull << lane) - 1ull));
    int wtot = __popcll(m);
    if (lane == 0) wsum[wv] = wtot;
    __syncthreads();
    int prev = 0;
    for (int ww = 0; ww < wv; ++ww) prev += wsum[ww];
    int tot = wsum[0] + wsum[1] + wsum[2] + wsum[3];
    if (f) {
      int pos = base + prev + rank;
      toklist[e * 8192 + pos] = t;
      wlist[e * 8192 + pos] = wt;
    }
    base += tot;
    __syncthreads();
  }
  if (tid == 0) cnt[e] = base;
}

// ---- MFMA bf16 GEMM: 64x64 tile, BK=32, 4 waves, 16x16x32 frags ----
// XMODE: 0 dense f32, 1 dense bf16, 2 gathered f32 rows (toklist)
// ACT: 0 none, 1 silu, 2 tanh
// OUTMODE: 0 f32 store, 1 f32 +=, 2 bf16 store, 3 weighted scatter-atomicAdd (expertB)
// EXPERT: blockIdx.z = expert; W/bias strided; rows bounded by cnt[e]-chunk0;
//         Xb/C16 offset by e*hidstride (PER-EXPERT hid regions — fixes R5 race)
template<int XMODE, int ACT, int OUTMODE, int EXPERT>
__global__ __launch_bounds__(256) void mfma_gemm(
    const float* __restrict__ Xf, const u16* __restrict__ Xb,
    const float* __restrict__ Wg, const float* __restrict__ biasg,
    float* __restrict__ C, u16* __restrict__ C16,
    const int* __restrict__ toklist, const float* __restrict__ wlist,
    const int* __restrict__ cnt, int M, int K, int N, int chunk0,
    size_t hidstride, float* __restrict__ moe) {
  int e = EXPERT ? blockIdx.z : 0;
  const float* W = Wg + (size_t)e * K * N;
  const float* bias = biasg + (size_t)e * N;
  int Mloc = M;
  if (EXPERT) {
    int ce = cnt[e]; if (ce > 8192) ce = 8192;
    Mloc = ce - chunk0;
    if (XMODE == 1) Xb += (size_t)e * hidstride;     // per-expert hid region
    if (OUTMODE == 2) C16 += (size_t)e * hidstride;  // per-expert hid region
  }
  const int bm = blockIdx.y << 6, bn = blockIdx.x << 6;
  if (EXPERT && bm >= Mloc) return;
  __shared__ u16 As[64][40];
  __shared__ u16 Bs[64][40];
  __shared__ int rows[64];
  const int tid = threadIdx.x;
  if (EXPERT && XMODE == 2 && tid < 64) {
    int ce = cnt[e]; if (ce > 8192) ce = 8192;
    int r = chunk0 + bm + tid;
    rows[tid] = toklist[e * 8192 + (r < ce ? r : chunk0)] & 8191;
  }
  const int srow = tid >> 2;          // 0..63
  const int skg = (tid & 3) << 3;     // 0,8,16,24
  const int wv = tid >> 6, lane = tid & 63, q = lane >> 4, m16 = lane & 15;
  f32x4 acc[4];
  #pragma unroll
  for (int c = 0; c < 4; ++c)
    #pragma unroll
    for (int i = 0; i < 4; ++i) acc[c][i] = 0.f;

  for (int k0 = 0; k0 < K; k0 += 32) {
    __syncthreads();
    // stage A tile (64 rows x 32 k) as bf16
    {
      u16 a8[8] __attribute__((aligned(16)));
      if (XMODE == 1) {
        *(uint4*)a8 = *(const uint4*)(Xb + (size_t)(bm + srow) * K + k0 + skg);
      } else {
        const float* src = (XMODE == 2) ? (Xf + (size_t)rows[srow] * K + k0 + skg)
                                        : (Xf + (size_t)(bm + srow) * K + k0 + skg);
        float4 x0 = *(const float4*)(src);
        float4 x1 = *(const float4*)(src + 4);
        a8[0] = f2b(x0.x); a8[1] = f2b(x0.y); a8[2] = f2b(x0.z); a8[3] = f2b(x0.w);
        a8[4] = f2b(x1.x); a8[5] = f2b(x1.y); a8[6] = f2b(x1.z); a8[7] = f2b(x1.w);
      }
      *(uint4*)&As[srow][skg] = *(uint4*)a8;
    }
    // stage B tile transposed: Bs[n][k] = W[k0+k][bn+n]
    {
      u16 b8[8] __attribute__((aligned(16)));
      const float* src = W + (size_t)(k0 + skg) * N + bn + srow;
      #pragma unroll
      for (int j = 0; j < 8; ++j) b8[j] = f2b(src[(size_t)j * N]);
      *(uint4*)&Bs[srow][skg] = *(uint4*)b8;
    }
    __syncthreads();
    short8 af = *(const short8*)&As[wv * 16 + m16][q * 8];
    #pragma unroll
    for (int c = 0; c < 4; ++c) {
      short8 bf = *(const short8*)&Bs[c * 16 + m16][q * 8];
      acc[c] = __builtin_amdgcn_mfma_f32_16x16x32_bf16(af, bf, acc[c], 0, 0, 0);
    }
  }
  // epilogue: lane holds D[row=q*4+i][col=c*16+m16], wave rows base wv*16
  #pragma unroll
  for (int c = 0; c < 4; ++c) {
    int col = bn + c * 16 + m16;
    float bb = bias[col];
    #pragma unroll
    for (int i = 0; i < 4; ++i) {
      int rl = bm + wv * 16 + q * 4 + i;
      if (EXPERT && rl >= Mloc) continue;
      float v = acc[c][i] + bb;
      if (ACT == 1) v = v / (1.f + expf(-v));
      else if (ACT == 2) v = tanhf(v);
      if (OUTMODE == 0) C[(size_t)rl * N + col] = v;
      else if (OUTMODE == 1) C[(size_t)rl * N + col] += v;
      else if (OUTMODE == 2) C16[(size_t)rl * N + col] = f2b(v);
      else {  // weighted scatter into moe
        int rg = chunk0 + rl;
        int tok = toklist[e * 8192 + rg] & 8191;
        float wt = wlist[e * 8192 + rg];
        atomicAdd(&moe[(size_t)tok * 512 + col], v * wt);
      }
    }
  }
}

// ---- halt head ----
__global__ __launch_bounds__(256) void k_halt(const u16* __restrict__ hh, const float* __restrict__ hW2,
                                              const float* __restrict__ hb2, float* __restrict__ out) {
  int lane = threadIdx.x & 63, wid = threadIdx.x >> 6;
  int t = blockIdx.x * 4 + wid;
  const u16* x = hh + (size_t)t * 256;
  float a = b2f(x[lane]) * hW2[lane] + b2f(x[lane + 64]) * hW2[lane + 64] +
            b2f(x[lane + 128]) * hW2[lane + 128] + b2f(x[lane + 192]) * hW2[lane + 192];
  #pragma unroll
  for (int off = 32; off; off >>= 1) a += __shfl_xor(a, off);
  if (lane == 0) {
    float p = 1.f / (1.f + expf(-(a + hb2[0])));
    out[4194304 + t] = p;
    out[4194304 + 8192 + t] = p;
  }
}

// ---- scalar: stab + aux loss ----
__global__ __launch_bounds__(256) void k_final(const float* __restrict__ probs, const int* __restrict__ cnt,
                                               const float* __restrict__ lA, float* __restrict__ out) {
  __shared__ float sp[4][8];
  __shared__ float sm[4];
  int tid = threadIdx.x, lane = tid & 63, wid = tid >> 6;
  float part[8] = {};
  for (int i = tid; i < 8192; i += 256) {
    const float* p = probs + i * 8;
    #pragma unroll
    for (int e = 0; e < 8; ++e) part[e] += p[e];
  }
  #pragma unroll
  for (int off = 32; off; off >>= 1)
    #pragma unroll
    for (int e = 0; e < 8; ++e) part[e] += __shfl_xor(part[e], off);
  float mx = 0.f;
  for (int d = tid; d < 512; d += 256) mx = fmaxf(mx, expf(lA[d]));
  #pragma unroll
  for (int off = 32; off; off >>= 1) mx = fmaxf(mx, __shfl_xor(mx, off));
  if (lane == 0) {
    #pragma unroll
    for (int e = 0; e < 8; ++e) sp[wid][e] = part[e];
    sm[wid] = mx;
  }
  __syncthreads();
  if (tid == 0) {
    float loss = 0.f;
    for (int e = 0; e < 8; ++e) {
      float pm = (sp[0][e] + sp[1][e] + sp[2][e] + sp[3][e]) * (1.f / 8192.f);
      int c = cnt[e]; if (c > 8192) c = 8192;
      loss += (float)c * (1.f / 8192.f) * pm;
    }
    loss *= 0.01f * 8.f;
    float mall = fmaxf(fmaxf(sm[0], sm[1]), fmaxf(sm[2], sm[3]));
    out[4194304 + 16384] = fmaxf(mall - 0.95f, 0.f) + loss;
  }
}

extern "C" void kernel_launch(void* const* d_in, const int* in_sizes, int n_in,
                              void* d_out, int out_size, void* d_ws, size_t ws_size,
                              hipStream_t stream) {
  const float* h   = (const float*)d_in[0];
  const float* ef  = (const float*)d_in[1];
  const float* lA  = (const float*)d_in[2];
  const float* Bw  = (const float*)d_in[3];
  const float* Bb  = (const float*)d_in[4];
  const float* Wq  = (const float*)d_in[5];  const float* bq  = (const float*)d_in[6];
  const float* Wk  = (const float*)d_in[7];  const float* bk  = (const float*)d_in[8];
  const float* Wv  = (const float*)d_in[9];  const float* bv  = (const float*)d_in[10];
  const float* Wo  = (const float*)d_in[11]; const float* bo  = (const float*)d_in[12];
  const float* n1g = (const float*)d_in[13]; const float* n1b = (const float*)d_in[14];
  const float* n2g = (const float*)d_in[15]; const float* n2b = (const float*)d_in[16];
  const float* n3g = (const float*)d_in[17]; const float* n3b = (const float*)d_in[18];
  const float* gw  = (const float*)d_in[19]; const float* gb  = (const float*)d_in[20];
  const float* eW1 = (const float*)d_in[21]; const float* eb1 = (const float*)d_in[22];
  const float* eW2 = (const float*)d_in[23]; const float* eb2 = (const float*)d_in[24];
  const float* sW1 = (const float*)d_in[25]; const float* sb1 = (const float*)d_in[26];
  const float* sW2 = (const float*)d_in[27]; const float* sb2 = (const float*)d_in[28];
  const float* hW1 = (const float*)d_in[29]; const float* hb1 = (const float*)d_in[30];
  const float* hW2 = (const float*)d_in[31]; const float* hb2 = (const float*)d_in[32];
  float* out = (float*)d_out;
  float* ws = (float*)d_ws;

  // ---- tiered workspace layout (runtime-sized) ----
  // [0,R) h2 | [R,2R) moe | [2R,2R+ARENA) arena | small scratch
  // arena reused: attention (hlti|q|k|v, ao->q hp->k) -> hid bf16 [8][CAPE][1024] -> hh bf16
  const size_t R = (size_t)TT * DD;   // 4,194,304 floats
  const size_t SM = 155648 + 73744;   // floats + ints
  size_t wsf = ws_size / 4;
  int S; size_t ARENA;
  if (wsf >= 6 * R + SM)      { S = 8192; ARENA = 4 * R; }
  else if (wsf >= 3 * R + SM) { S = 2048; ARENA = R; }
  else                        { S = 512;  ARENA = 1048576; }
  // routed-expert per-expert chunk rows: 8*CAPE*1024 u16 == ARENA*4 bytes
  const int CAPE = (int)(ARENA / 4096);          // 4096 / 1024 / 256
  const int NCH  = 8192 / CAPE;                  // worst-case chunks (cnt[e] <= 8192)
  const size_t HIDSTRIDE = (size_t)CAPE * 1024;  // u16 elements per expert region
  // shared-expert chunk rows: CAPS*1024 u16 <= ARENA*4 bytes
  const int CAPS = (ARENA / 512 >= 8192) ? 8192 : (int)(ARENA / 512);  // 8192 / 8192 / 2048

  float* f_h2  = ws;
  float* f_moe = ws + R;
  float* arena = ws + 2 * R;
  const size_t SD = (size_t)S * 512;
  float* f_hlti = arena;
  float* f_q = arena + SD;
  float* f_k = arena + 2 * SD;
  float* f_v = arena + 3 * SD;
  float* f_ao = f_q;
  float* f_hp = f_k;
  u16* f_hid = (u16*)arena;
  u16* f_hh  = (u16*)arena;
  float* smr = ws + 2 * R + ARENA;
  float* f_esum = smr;
  float* f_einj = smr + 4096;
  float* f_probs = smr + 8192;
  float2* f_wpair = (float2*)(smr + 8192 + 65536);
  float* f_wlist = smr + 8192 + 65536 + 16384;
  int* ip = (int*)(smr + 8192 + 65536 + 16384 + 65536);
  int* sel = ip; int* cnt = ip + 8192; int* toklist = ip + 8192 + 16;

  // ---- LTI prep ----
  k_zero<<<16, 256, 0, stream>>>(f_esum);
  k_esum<<<dim3(8, 32), 256, 0, stream>>>(ef, f_esum);
  k_einj<<<16, 256, 0, stream>>>(f_esum, Bw, Bb, f_einj);

  // ---- LTI + attention (f32, routing-critical) ----
  for (int s = 0; s < TT / S; ++s) {
    int seg0 = s * S;
    k_lti<<<S, 256, 0, stream>>>(h, lA, f_einj, n1g, n1b, f_hlti, seg0);
    gemm_qkv<<<dim3(8, S / 64, 3), 256, 0, stream>>>(f_hlti, Wq, bq, Wk, bk, Wv, bv, f_q, f_k, f_v);
    k_attn<<<S, 64, 0, stream>>>(f_q, f_k, f_v, f_ao);
    gemm_f32<<<dim3(8, S / 64), 256, 0, stream>>>(f_ao, Wo, bo, f_hp, 512, 512);
    k_ln_res<<<S, 256, 0, stream>>>(f_hlti, f_hp, n2g, n2b, f_h2 + (size_t)seg0 * 512);
  }

  // ---- gate: two-phase, no contended atomics ----
  k_gateA<<<TT / 4, 256, 0, stream>>>(f_h2, gw, gb, f_probs, sel, f_wpair);
  k_gateB<<<8, 256, 0, stream>>>(sel, f_wpair, toklist, f_wlist, cnt);

  // ---- shared experts (MFMA), chunked by CAPS ----
  for (int sx = 0; sx < 2; ++sx)
    for (int c = 0; c < TT / CAPS; ++c) {
      const float* xs = f_h2 + (size_t)c * CAPS * 512;
      float* ms = f_moe + (size_t)c * CAPS * 512;
      mfma_gemm<0,1,2,0><<<dim3(16, CAPS / 64), 256, 0, stream>>>(
          xs, nullptr, sW1 + (size_t)sx * 524288, sb1 + sx * 1024,
          nullptr, f_hid, nullptr, nullptr, nullptr, CAPS, 512, 1024, 0, 0, nullptr);
      if (sx == 0)
        mfma_gemm<1,0,0,0><<<dim3(8, CAPS / 64), 256, 0, stream>>>(
            nullptr, f_hid, sW2, sb2, ms, nullptr, nullptr, nullptr, nullptr, CAPS, 1024, 512, 0, 0, nullptr);
      else
        mfma_gemm<1,0,1,0><<<dim3(8, CAPS / 64), 256, 0, stream>>>(
            nullptr, f_hid, sW2 + 524288, sb2 + 512, ms, nullptr, nullptr, nullptr, nullptr, CAPS, 1024, 512, 0, 0, nullptr);
    }

  // ---- routed experts (MFMA, gathered, grid.z=8, PER-EXPERT hid regions) ----
  for (int c = 0; c < NCH; ++c) {
    mfma_gemm<2,1,2,1><<<dim3(16, CAPE / 64, 8), 256, 0, stream>>>(
        f_h2, nullptr, eW1, eb1, nullptr, f_hid, toklist, nullptr, cnt,
        CAPE, 512, 1024, c * CAPE, HIDSTRIDE, nullptr);
    mfma_gemm<1,0,3,1><<<dim3(8, CAPE / 64, 8), 256, 0, stream>>>(
        nullptr, f_hid, eW2, eb2, nullptr, nullptr, toklist, f_wlist, cnt,
        CAPE, 1024, 512, c * CAPE, HIDSTRIDE, f_moe);
  }

  // ---- final LN -> out (h3 f32), halt head (MFMA), scalars ----
  k_ln_res<<<TT, 256, 0, stream>>>(f_h2, f_moe, n3g, n3b, out);
  mfma_gemm<0,2,2,0><<<dim3(4, 128), 256, 0, stream>>>(
      out, nullptr, hW1, hb1, nullptr, f_hh, nullptr, nullptr, nullptr, TT, 512, 256, 0, 0, nullptr);
  k_halt<<<TT / 4, 256, 0, stream>>>(f_hh, hW2, hb2, out);
  k_final<<<1, 256, 0, stream>>>(f_probs, cnt, lA, out);
}